// Round 1
// baseline (191.835 us; speedup 1.0000x reference)
//
#include <hip/hip_runtime.h>

#define SEQ 2048
#define NH 16
#define HD 64
#define EMB 1024

typedef __attribute__((ext_vector_type(4))) float f32x4;
typedef __attribute__((ext_vector_type(8))) __bf16 bf16x8;

__device__ inline unsigned short f2bf(float f){
  unsigned int u = __float_as_uint(f);
  return (unsigned short)((u + 0x7fffu + ((u >> 16) & 1u)) >> 16);
}
__device__ inline float bf2f(unsigned short h){ return __uint_as_float(((unsigned int)h) << 16); }

// ---------------- x f32 -> bf16 ----------------
__global__ __launch_bounds__(256) void k_convert(const float* __restrict__ in,
                                                 unsigned short* __restrict__ out, int n8){
  int i = blockIdx.x * 256 + threadIdx.x;
  if (i >= n8) return;
  const float4* p = (const float4*)in + (size_t)i * 2;
  float4 a = p[0], b = p[1];
  uint4 r;
  r.x = f2bf(a.x) | ((unsigned)f2bf(a.y) << 16);
  r.y = f2bf(a.z) | ((unsigned)f2bf(a.w) << 16);
  r.z = f2bf(b.x) | ((unsigned)f2bf(b.y) << 16);
  r.w = f2bf(b.z) | ((unsigned)f2bf(b.w) << 16);
  ((uint4*)out)[i] = r;
}

// ------------- W [K][N] f32 -> Wt [N][K] bf16 (tile transpose) -------------
__global__ __launch_bounds__(256) void k_transpose_w(const float* __restrict__ Wq, const float* __restrict__ Wk,
                                                     const float* __restrict__ Wv, const float* __restrict__ Wo,
                                                     unsigned short* __restrict__ WtQKV,
                                                     unsigned short* __restrict__ WtO){
  int z = blockIdx.z;
  const float* W = (z == 0) ? Wq : (z == 1) ? Wk : (z == 2) ? Wv : Wo;
  unsigned short* out = (z < 3) ? (WtQKV + (size_t)z * EMB * EMB) : WtO;
  __shared__ float t[32][33];
  int n0 = blockIdx.x * 32, k0 = blockIdx.y * 32;
  int tx = threadIdx.x, ty = threadIdx.y;
  #pragma unroll
  for (int i = 0; i < 4; ++i)
    t[ty + i * 8][tx] = W[(size_t)(k0 + ty + i * 8) * EMB + n0 + tx];
  __syncthreads();
  #pragma unroll
  for (int i = 0; i < 4; ++i)
    out[(size_t)(n0 + ty + i * 8) * EMB + k0 + tx] = f2bf(t[tx][ty + i * 8]);
}

// ---------------- RoPE cos/sin table [S][32] ----------------
__global__ __launch_bounds__(256) void k_rope_table(float2* __restrict__ tb){
  int idx = blockIdx.x * 256 + threadIdx.x;   // 65536
  int s = idx >> 5, j = idx & 31;
  float invf = __expf(-(float)j * (9.210340371976184f / 32.0f));  // 10000^(-j/32)
  float ang = (float)s * invf;
  tb[idx] = make_float2(cosf(ang), sinf(ang));
}

// ---------------- GEMM: C[M=4096][N] = A[M][1024] * Bt[N][1024]^T ----------------
// MODE 0: N=3072, scatter to Q/K/V [B*H][S][D] bf16.  MODE 1: N=1024, f32 out.
template<int MODE>
__global__ __launch_bounds__(256, 2) void k_gemm(const unsigned short* __restrict__ A,
                                                 const unsigned short* __restrict__ Bt,
                                                 unsigned short* __restrict__ Qb,
                                                 unsigned short* __restrict__ Kb,
                                                 unsigned short* __restrict__ Vb,
                                                 float* __restrict__ FO){
  const int Kd = 1024;
  int m0 = blockIdx.x * 128, n0 = blockIdx.y * 128;
  int tid = threadIdx.x;
  int w = tid >> 6, lane = tid & 63;
  int wm = w >> 1, wn = w & 1;
  int g = lane >> 4, lr = lane & 15;
  __shared__ unsigned short Ash[128 * 64];
  __shared__ unsigned short Bsh[128 * 64];
  f32x4 acc[4][4] = {};
  int r_ = tid >> 3, c_ = tid & 7;
  int rm = r_ & 7;                // (row & 7) for the staged rows
  int cc = c_ ^ rm;               // pre-swizzled source chunk (rule #21)
  for (int kt = 0; kt < Kd / 64; ++kt){
    int kb = kt * 64;
    #pragma unroll
    for (int it = 0; it < 4; ++it){
      int row = it * 32 + r_;
      __builtin_amdgcn_global_load_lds(
        (const __attribute__((address_space(1))) void*)(A + (size_t)(m0 + row) * Kd + kb + cc * 8),
        (__attribute__((address_space(3))) void*)(Ash + it * 2048 + tid * 8), 16, 0, 0);
      __builtin_amdgcn_global_load_lds(
        (const __attribute__((address_space(1))) void*)(Bt + (size_t)(n0 + row) * Kd + kb + cc * 8),
        (__attribute__((address_space(3))) void*)(Bsh + it * 2048 + tid * 8), 16, 0, 0);
    }
    __syncthreads();
    #pragma unroll
    for (int kk = 0; kk < 2; ++kk){
      bf16x8 af[4], bfr[4];
      #pragma unroll
      for (int i = 0; i < 4; ++i){
        int ra = wm * 64 + i * 16 + lr;
        af[i]  = *(const bf16x8*)(Ash + ra * 64 + (((kk * 4 + g) ^ (ra & 7)) * 8));
        int rb = wn * 64 + i * 16 + lr;
        bfr[i] = *(const bf16x8*)(Bsh + rb * 64 + (((kk * 4 + g) ^ (rb & 7)) * 8));
      }
      #pragma unroll
      for (int mi = 0; mi < 4; ++mi)
        #pragma unroll
        for (int ni = 0; ni < 4; ++ni)
          acc[mi][ni] = __builtin_amdgcn_mfma_f32_16x16x32_bf16(af[mi], bfr[ni], acc[mi][ni], 0, 0, 0);
    }
    __syncthreads();
  }
  #pragma unroll
  for (int mi = 0; mi < 4; ++mi){
    #pragma unroll
    for (int ni = 0; ni < 4; ++ni){
      int col = n0 + wn * 64 + ni * 16 + lr;
      #pragma unroll
      for (int r = 0; r < 4; ++r){
        int mrow = m0 + wm * 64 + mi * 16 + 4 * g + r;   // = b*S + s
        float v = acc[mi][ni][r];
        if constexpr (MODE == 0){
          int mat = col >> 10, e = col & 1023;
          int h = e >> 6, d = e & 63;
          int bb = mrow >> 11, s = mrow & 2047;
          size_t off = ((size_t)((bb * NH + h) * SEQ + s)) * HD + d;
          unsigned short* dst = (mat == 0) ? Qb : (mat == 1) ? Kb : Vb;
          dst[off] = f2bf(v);
        } else {
          FO[(size_t)mrow * EMB + col] = v;
        }
      }
    }
  }
}

// ---------------- RoPE in-place on Q and K ([B*H][S][64] bf16) ----------------
__global__ __launch_bounds__(256) void k_rope(unsigned short* __restrict__ Qb,
                                              unsigned short* __restrict__ Kb,
                                              const float2* __restrict__ tb){
  int rid = blockIdx.x * 8 + (threadIdx.x >> 5);   // 0..131071
  int j = threadIdx.x & 31;
  int which = rid >> 16;                            // 0=Q rows, 1=K rows (65536 each)
  int rem = rid & 65535;                            // = bh*2048 + s
  int s = rem & 2047;
  unsigned short* base = (which ? Kb : Qb) + (size_t)rem * 64;
  unsigned int eo = *(const unsigned int*)(base + 2 * j);   // elems 2j, 2j+1
  float ej = bf2f((unsigned short)(eo & 0xffff));
  float oj = bf2f((unsigned short)(eo >> 16));
  float a_e = __shfl(ej, (j >> 1), 32);
  float a_o = __shfl(oj, (j >> 1), 32);
  float h_e = __shfl(ej, 16 + (j >> 1), 32);
  float h_o = __shfl(oj, 16 + (j >> 1), 32);
  float aval = (j & 1) ? a_o : a_e;    // q[j]
  float hval = (j & 1) ? h_o : h_e;    // q[32+j]
  float2 cs = tb[s * 32 + j];
  base[j]      = f2bf(aval * cs.x - oj * cs.y);   // q[j]c - q[2j+1]s
  base[32 + j] = f2bf(hval * cs.x + ej * cs.y);   // q[32+j]c + q[2j]s
}

// ---------------- V [bh][S][64] -> Vt [bh][64][S] ----------------
__global__ __launch_bounds__(256) void k_transpose_v(const unsigned short* __restrict__ V,
                                                     unsigned short* __restrict__ Vt){
  int bh = blockIdx.z;
  const unsigned short* src = V + (size_t)bh * SEQ * HD;
  unsigned short* dst = Vt + (size_t)bh * HD * SEQ;
  __shared__ unsigned short t[32][33];
  int s0 = blockIdx.x * 32, d0 = blockIdx.y * 32;
  int tx = threadIdx.x, ty = threadIdx.y;
  #pragma unroll
  for (int i = 0; i < 4; ++i)
    t[ty + i * 8][tx] = src[(size_t)(s0 + ty + i * 8) * HD + d0 + tx];
  __syncthreads();
  #pragma unroll
  for (int i = 0; i < 4; ++i)
    dst[(size_t)(d0 + ty + i * 8) * SEQ + s0 + tx] = t[tx][ty + i * 8];
}

// ---------------- causal flash attention ----------------
// grid (16, 32); 4 waves; wave owns 32 q rows; KVBLK=64; K,V frags direct from global.
__global__ __launch_bounds__(256, 2) void k_attn(const unsigned short* __restrict__ Qb,
                                                 const unsigned short* __restrict__ Kb,
                                                 const unsigned short* __restrict__ Vt,
                                                 unsigned short* __restrict__ AO){
  int bh = blockIdx.y;
  int bx = blockIdx.x;
  int qi = (bx & 1) ? (15 - (bx >> 1)) : (bx >> 1);   // balance causal work
  int wid = threadIdx.x >> 6, lane = threadIdx.x & 63;
  int g = lane >> 4, lr = lane & 15;
  int q0 = qi * 128 + wid * 32;
  const unsigned short* Qp = Qb + (size_t)bh * SEQ * HD;
  const unsigned short* Kp = Kb + (size_t)bh * SEQ * HD;
  const unsigned short* Vp = Vt + (size_t)bh * HD * SEQ;
  __shared__ unsigned short Pl[4][32 * 64];
  unsigned short* Pw = Pl[wid];

  bf16x8 aq[2][2];
  #pragma unroll
  for (int mi = 0; mi < 2; ++mi)
    #pragma unroll
    for (int kk = 0; kk < 2; ++kk)
      aq[mi][kk] = *(const bf16x8*)(Qp + (size_t)(q0 + mi * 16 + lr) * HD + kk * 32 + g * 8);

  f32x4 ov[2][4] = {};
  float mS[8], lS[8];
  #pragma unroll
  for (int i = 0; i < 8; ++i){ mS[i] = -1e30f; lS[i] = 0.f; }

  int nt = (q0 >> 6) + 1;
  for (int t = 0; t < nt; ++t){
    int kv0 = t * 64;
    bool maskt = (t == nt - 1);
    bf16x8 bk[4][2];
    #pragma unroll
    for (int nj = 0; nj < 4; ++nj)
      #pragma unroll
      for (int kk = 0; kk < 2; ++kk)
        bk[nj][kk] = *(const bf16x8*)(Kp + (size_t)(kv0 + nj * 16 + lr) * HD + kk * 32 + g * 8);
    f32x4 sf[2][4];
    #pragma unroll
    for (int mi = 0; mi < 2; ++mi)
      #pragma unroll
      for (int nj = 0; nj < 4; ++nj){
        f32x4 z = {0.f, 0.f, 0.f, 0.f};
        z = __builtin_amdgcn_mfma_f32_16x16x32_bf16(aq[mi][0], bk[nj][0], z, 0, 0, 0);
        z = __builtin_amdgcn_mfma_f32_16x16x32_bf16(aq[mi][1], bk[nj][1], z, 0, 0, 0);
        sf[mi][nj] = z;
      }
    float tmax[8];
    #pragma unroll
    for (int i = 0; i < 8; ++i) tmax[i] = -1e30f;
    #pragma unroll
    for (int mi = 0; mi < 2; ++mi)
      #pragma unroll
      for (int nj = 0; nj < 4; ++nj)
        #pragma unroll
        for (int r = 0; r < 4; ++r){
          float v = sf[mi][nj][r] * 0.125f;
          if (maskt){
            int qg = q0 + mi * 16 + 4 * g + r;
            int kvg = kv0 + nj * 16 + lr;
            if (kvg > qg) v = -1e30f;
          }
          sf[mi][nj][r] = v;
          tmax[mi * 4 + r] = fmaxf(tmax[mi * 4 + r], v);
        }
    #pragma unroll
    for (int i = 0; i < 8; ++i)
      #pragma unroll
      for (int d = 1; d < 16; d <<= 1)
        tmax[i] = fmaxf(tmax[i], __shfl_xor(tmax[i], d, 64));
    float al[8];
    #pragma unroll
    for (int i = 0; i < 8; ++i){
      float mn = fmaxf(mS[i], tmax[i]);
      al[i] = __expf(mS[i] - mn);
      mS[i] = mn;
    }
    float ps[8] = {0, 0, 0, 0, 0, 0, 0, 0};
    #pragma unroll
    for (int mi = 0; mi < 2; ++mi)
      #pragma unroll
      for (int nj = 0; nj < 4; ++nj)
        #pragma unroll
        for (int r = 0; r < 4; ++r){
          float p = __expf(sf[mi][nj][r] - mS[mi * 4 + r]);
          ps[mi * 4 + r] += p;
          int row = mi * 16 + 4 * g + r;
          int colb = (nj * 16 + lr) * 2;
          *(unsigned short*)((char*)Pw + row * 128 + (colb ^ ((row & 7) << 4))) = f2bf(p);
        }
    #pragma unroll
    for (int i = 0; i < 8; ++i){
      #pragma unroll
      for (int d = 1; d < 16; d <<= 1)
        ps[i] += __shfl_xor(ps[i], d, 64);
      lS[i] = lS[i] * al[i] + ps[i];
    }
    #pragma unroll
    for (int mi = 0; mi < 2; ++mi)
      #pragma unroll
      for (int dj = 0; dj < 4; ++dj)
        #pragma unroll
        for (int r = 0; r < 4; ++r)
          ov[mi][dj][r] *= al[mi * 4 + r];
    #pragma unroll
    for (int kk = 0; kk < 2; ++kk){
      bf16x8 pa[2];
      #pragma unroll
      for (int mi = 0; mi < 2; ++mi){
        int row = mi * 16 + lr;
        pa[mi] = *(const bf16x8*)((char*)Pw + row * 128 + (((kk * 4 + g) ^ (row & 7)) << 4));
      }
      bf16x8 bv[4];
      #pragma unroll
      for (int dj = 0; dj < 4; ++dj)
        bv[dj] = *(const bf16x8*)(Vp + (size_t)(dj * 16 + lr) * SEQ + kv0 + kk * 32 + g * 8);
      #pragma unroll
      for (int mi = 0; mi < 2; ++mi)
        #pragma unroll
        for (int dj = 0; dj < 4; ++dj)
          ov[mi][dj] = __builtin_amdgcn_mfma_f32_16x16x32_bf16(pa[mi], bv[dj], ov[mi][dj], 0, 0, 0);
    }
  }
  int b = bh >> 4, h = bh & 15;
  #pragma unroll
  for (int i = 0; i < 8; ++i) lS[i] = 1.0f / lS[i];
  #pragma unroll
  for (int mi = 0; mi < 2; ++mi)
    #pragma unroll
    for (int dj = 0; dj < 4; ++dj)
      #pragma unroll
      for (int r = 0; r < 4; ++r){
        int qg = q0 + mi * 16 + 4 * g + r;
        AO[((size_t)(b * SEQ + qg)) * EMB + h * HD + dj * 16 + lr] = f2bf(ov[mi][dj][r] * lS[mi * 4 + r]);
      }
}

extern "C" void kernel_launch(void* const* d_in, const int* in_sizes, int n_in,
                              void* d_out, int out_size, void* d_ws, size_t ws_size,
                              hipStream_t stream){
  const float* x  = (const float*)d_in[0];
  const float* Wq = (const float*)d_in[2];
  const float* Wk = (const float*)d_in[3];
  const float* Wv = (const float*)d_in[4];
  const float* Wo = (const float*)d_in[5];
  float* out = (float*)d_out;

  char* ws = (char*)d_ws;
  size_t off = 0;
  auto alloc = [&](size_t bytes){ void* p = ws + off; off += (bytes + 255) & ~(size_t)255; return p; };
  unsigned short* xb    = (unsigned short*)alloc((size_t)4096 * 1024 * 2);
  unsigned short* wtqkv = (unsigned short*)alloc((size_t)3072 * 1024 * 2);
  unsigned short* wto   = (unsigned short*)alloc((size_t)1024 * 1024 * 2);
  unsigned short* qb    = (unsigned short*)alloc((size_t)4096 * 1024 * 2);
  unsigned short* kb    = (unsigned short*)alloc((size_t)4096 * 1024 * 2);
  unsigned short* vb    = (unsigned short*)alloc((size_t)4096 * 1024 * 2);
  float2*         tb    = (float2*)alloc((size_t)2048 * 32 * 8);
  unsigned short* vt = xb;   // xb dead after QKV GEMM
  unsigned short* ao = vb;   // vb dead after V transpose

  k_convert<<<dim3(2048), dim3(256), 0, stream>>>(x, xb, 524288);
  k_transpose_w<<<dim3(32, 32, 4), dim3(32, 8), 0, stream>>>(Wq, Wk, Wv, Wo, wtqkv, wto);
  k_rope_table<<<dim3(256), dim3(256), 0, stream>>>(tb);
  k_gemm<0><<<dim3(32, 24), dim3(256), 0, stream>>>(xb, wtqkv, qb, kb, vb, nullptr);
  k_rope<<<dim3(16384), dim3(256), 0, stream>>>(qb, kb, tb);
  k_transpose_v<<<dim3(64, 2, 32), dim3(32, 8), 0, stream>>>(vb, vt);
  k_attn<<<dim3(16, 32), dim3(256), 0, stream>>>(qb, kb, vt, ao);
  k_gemm<1><<<dim3(32, 8), dim3(256), 0, stream>>>(ao, wto, nullptr, nullptr, nullptr, out);
}

// Round 2
// 166.101 us; speedup vs baseline: 1.1549x; 1.1549x over previous
//
#include <hip/hip_runtime.h>

#define SEQ 2048
#define NH 16
#define HD 64
#define EMB 1024

typedef __attribute__((ext_vector_type(4))) float f32x4;
typedef __attribute__((ext_vector_type(16))) float f32x16;
typedef __attribute__((ext_vector_type(8))) __bf16 bf16x8;
typedef unsigned int u32x2 __attribute__((ext_vector_type(2)));

__device__ inline unsigned short f2bf(float f){
  unsigned int u = __float_as_uint(f);
  return (unsigned short)((u + 0x7fffu + ((u >> 16) & 1u)) >> 16);
}
__device__ inline float bf2f(unsigned short h){ return __uint_as_float(((unsigned int)h) << 16); }

__device__ inline unsigned cvtpk(float lo, float hi){
  unsigned r;
  asm("v_cvt_pk_bf16_f32 %0, %1, %2" : "=v"(r) : "v"(lo), "v"(hi));
  return r;
}
__device__ inline u32x2 plswap(unsigned a, unsigned b){
  return __builtin_amdgcn_permlane32_swap(a, b, false, false);
}

// ---------------- x f32 -> bf16 ----------------
__global__ __launch_bounds__(256) void k_convert(const float* __restrict__ in,
                                                 unsigned short* __restrict__ out, int n8){
  int i = blockIdx.x * 256 + threadIdx.x;
  if (i >= n8) return;
  const float4* p = (const float4*)in + (size_t)i * 2;
  float4 a = p[0], b = p[1];
  uint4 r;
  r.x = f2bf(a.x) | ((unsigned)f2bf(a.y) << 16);
  r.y = f2bf(a.z) | ((unsigned)f2bf(a.w) << 16);
  r.z = f2bf(b.x) | ((unsigned)f2bf(b.y) << 16);
  r.w = f2bf(b.z) | ((unsigned)f2bf(b.w) << 16);
  ((uint4*)out)[i] = r;
}

// ------------- W [K][N] f32 -> Wt [N][K] bf16 (tile transpose) -------------
__global__ __launch_bounds__(256) void k_transpose_w(const float* __restrict__ Wq, const float* __restrict__ Wk,
                                                     const float* __restrict__ Wv, const float* __restrict__ Wo,
                                                     unsigned short* __restrict__ WtQKV,
                                                     unsigned short* __restrict__ WtO){
  int z = blockIdx.z;
  const float* W = (z == 0) ? Wq : (z == 1) ? Wk : (z == 2) ? Wv : Wo;
  unsigned short* out = (z < 3) ? (WtQKV + (size_t)z * EMB * EMB) : WtO;
  __shared__ float t[32][33];
  int n0 = blockIdx.x * 32, k0 = blockIdx.y * 32;
  int tx = threadIdx.x, ty = threadIdx.y;
  #pragma unroll
  for (int i = 0; i < 4; ++i)
    t[ty + i * 8][tx] = W[(size_t)(k0 + ty + i * 8) * EMB + n0 + tx];
  __syncthreads();
  #pragma unroll
  for (int i = 0; i < 4; ++i)
    out[(size_t)(n0 + ty + i * 8) * EMB + k0 + tx] = f2bf(t[tx][ty + i * 8]);
}

// ---------------- RoPE cos/sin table [S][32] ----------------
__global__ __launch_bounds__(256) void k_rope_table(float2* __restrict__ tb){
  int idx = blockIdx.x * 256 + threadIdx.x;   // 65536
  int s = idx >> 5, j = idx & 31;
  float invf = __expf(-(float)j * (9.210340371976184f / 32.0f));  // 10000^(-j/32)
  float ang = (float)s * invf;
  tb[idx] = make_float2(cosf(ang), sinf(ang));
}

// ---------------- GEMM: C[M=4096][N] = A[M][1024] * Bt[N][1024]^T ----------------
// MODE 0: N=3072, scatter to Q/K/V [B*H][S][D] bf16 (Q pre-scaled by 0.125).
// MODE 1: N=1024, f32 out.
template<int MODE>
__global__ __launch_bounds__(256, 2) void k_gemm(const unsigned short* __restrict__ A,
                                                 const unsigned short* __restrict__ Bt,
                                                 unsigned short* __restrict__ Qb,
                                                 unsigned short* __restrict__ Kb,
                                                 unsigned short* __restrict__ Vb,
                                                 float* __restrict__ FO){
  const int Kd = 1024;
  int m0 = blockIdx.x * 128, n0 = blockIdx.y * 128;
  int tid = threadIdx.x;
  int w = tid >> 6, lane = tid & 63;
  int wm = w >> 1, wn = w & 1;
  int g = lane >> 4, lr = lane & 15;
  __shared__ unsigned short Ash[128 * 64];
  __shared__ unsigned short Bsh[128 * 64];
  f32x4 acc[4][4] = {};
  int r_ = tid >> 3, c_ = tid & 7;
  int rm = r_ & 7;                // (row & 7) for the staged rows
  int cc = c_ ^ rm;               // pre-swizzled source chunk (rule #21)
  for (int kt = 0; kt < Kd / 64; ++kt){
    int kb = kt * 64;
    #pragma unroll
    for (int it = 0; it < 4; ++it){
      int row = it * 32 + r_;
      __builtin_amdgcn_global_load_lds(
        (const __attribute__((address_space(1))) void*)(A + (size_t)(m0 + row) * Kd + kb + cc * 8),
        (__attribute__((address_space(3))) void*)(Ash + it * 2048 + tid * 8), 16, 0, 0);
      __builtin_amdgcn_global_load_lds(
        (const __attribute__((address_space(1))) void*)(Bt + (size_t)(n0 + row) * Kd + kb + cc * 8),
        (__attribute__((address_space(3))) void*)(Bsh + it * 2048 + tid * 8), 16, 0, 0);
    }
    __syncthreads();
    #pragma unroll
    for (int kk = 0; kk < 2; ++kk){
      bf16x8 af[4], bfr[4];
      #pragma unroll
      for (int i = 0; i < 4; ++i){
        int ra = wm * 64 + i * 16 + lr;
        af[i]  = *(const bf16x8*)(Ash + ra * 64 + (((kk * 4 + g) ^ (ra & 7)) * 8));
        int rb = wn * 64 + i * 16 + lr;
        bfr[i] = *(const bf16x8*)(Bsh + rb * 64 + (((kk * 4 + g) ^ (rb & 7)) * 8));
      }
      #pragma unroll
      for (int mi = 0; mi < 4; ++mi)
        #pragma unroll
        for (int ni = 0; ni < 4; ++ni)
          acc[mi][ni] = __builtin_amdgcn_mfma_f32_16x16x32_bf16(af[mi], bfr[ni], acc[mi][ni], 0, 0, 0);
    }
    __syncthreads();
  }
  #pragma unroll
  for (int mi = 0; mi < 4; ++mi){
    #pragma unroll
    for (int ni = 0; ni < 4; ++ni){
      int col = n0 + wn * 64 + ni * 16 + lr;
      #pragma unroll
      for (int r = 0; r < 4; ++r){
        int mrow = m0 + wm * 64 + mi * 16 + 4 * g + r;   // = b*S + s
        float v = acc[mi][ni][r];
        if constexpr (MODE == 0){
          int mat = col >> 10, e = col & 1023;
          int h = e >> 6, d = e & 63;
          int bb = mrow >> 11, s = mrow & 2047;
          size_t off = ((size_t)((bb * NH + h) * SEQ + s)) * HD + d;
          if (mat == 0) v *= 0.125f;   // fold 1/sqrt(D) into Q
          unsigned short* dst = (mat == 0) ? Qb : (mat == 1) ? Kb : Vb;
          dst[off] = f2bf(v);
        } else {
          FO[(size_t)mrow * EMB + col] = v;
        }
      }
    }
  }
}

// ---------------- RoPE in-place on Q and K ([B*H][S][64] bf16) ----------------
__global__ __launch_bounds__(256) void k_rope(unsigned short* __restrict__ Qb,
                                              unsigned short* __restrict__ Kb,
                                              const float2* __restrict__ tb){
  int rid = blockIdx.x * 8 + (threadIdx.x >> 5);   // 0..131071
  int j = threadIdx.x & 31;
  int which = rid >> 16;                            // 0=Q rows, 1=K rows (65536 each)
  int rem = rid & 65535;                            // = bh*2048 + s
  int s = rem & 2047;
  unsigned short* base = (which ? Kb : Qb) + (size_t)rem * 64;
  unsigned int eo = *(const unsigned int*)(base + 2 * j);   // elems 2j, 2j+1
  float ej = bf2f((unsigned short)(eo & 0xffff));
  float oj = bf2f((unsigned short)(eo >> 16));
  float a_e = __shfl(ej, (j >> 1), 32);
  float a_o = __shfl(oj, (j >> 1), 32);
  float h_e = __shfl(ej, 16 + (j >> 1), 32);
  float h_o = __shfl(oj, 16 + (j >> 1), 32);
  float aval = (j & 1) ? a_o : a_e;    // q[j]
  float hval = (j & 1) ? h_o : h_e;    // q[32+j]
  float2 cs = tb[s * 32 + j];
  base[j]      = f2bf(aval * cs.x - oj * cs.y);   // q[j]c - q[2j+1]s
  base[32 + j] = f2bf(hval * cs.x + ej * cs.y);   // q[32+j]c + q[2j]s
}

// ---------------- V [bh][S][64] -> Vt [bh][64][S] ----------------
__global__ __launch_bounds__(256) void k_transpose_v(const unsigned short* __restrict__ V,
                                                     unsigned short* __restrict__ Vt){
  int bh = blockIdx.z;
  const unsigned short* src = V + (size_t)bh * SEQ * HD;
  unsigned short* dst = Vt + (size_t)bh * HD * SEQ;
  __shared__ unsigned short t[32][33];
  int s0 = blockIdx.x * 32, d0 = blockIdx.y * 32;
  int tx = threadIdx.x, ty = threadIdx.y;
  #pragma unroll
  for (int i = 0; i < 4; ++i)
    t[ty + i * 8][tx] = src[(size_t)(s0 + ty + i * 8) * HD + d0 + tx];
  __syncthreads();
  #pragma unroll
  for (int i = 0; i < 4; ++i)
    dst[(size_t)(d0 + ty + i * 8) * SEQ + s0 + tx] = t[tx][ty + i * 8];
}

// ---------------- causal flash attention, swapped-QK^T in-register softmax ----------------
// one wave (64 thr) per block; wave owns 32 q rows; KVBLK=32; 32x32x16 MFMA.
// Q pre-scaled by 1/sqrt(D) in the QKV GEMM epilogue.
__global__ __launch_bounds__(64, 3) void k_attn(const unsigned short* __restrict__ Qb,
                                                const unsigned short* __restrict__ Kb,
                                                const unsigned short* __restrict__ Vt,
                                                unsigned short* __restrict__ AO){
  int b0 = blockIdx.x;               // 2048 blocks
  int seq = b0 >> 3;
  int bh = (b0 & 7) + 8 * (seq >> 6);   // group 4 bh per XCD slot -> K/V fits per-XCD L2
  int j = 63 - (seq & 63);              // long tasks first
  int q0 = j * 32;
  int l = threadIdx.x;
  int lr = l & 31, h = l >> 5;
  const unsigned short* Qp = Qb + (size_t)bh * SEQ * HD;
  const unsigned short* Kp = Kb + (size_t)bh * SEQ * HD;
  const unsigned short* Vp = Vt + (size_t)bh * HD * SEQ;

  // Q as B-operand: lane l holds Q[q0 + (l&31)][d = d0*16 + (l>>5)*8 + j]
  bf16x8 qf[4];
  #pragma unroll
  for (int d0 = 0; d0 < 4; ++d0)
    qf[d0] = *(const bf16x8*)(Qp + (size_t)(q0 + lr) * HD + d0 * 16 + h * 8);

  // K tile 0 as A-operand: lane l holds K[kv0 + (l&31)][same d slice]
  bf16x8 kf[4];
  #pragma unroll
  for (int d0 = 0; d0 < 4; ++d0)
    kf[d0] = *(const bf16x8*)(Kp + (size_t)lr * HD + d0 * 16 + h * 8);

  f32x16 ot0 = {}, ot1 = {};           // O^T accum: row=d-local, col=q
  float mS = -1e30f, lS = 0.f;
  int nt = j + 1;

  for (int t = 0; t < nt; ++t){
    int kv0 = t * 32;
    // V^T as A-operand for O^T = V^T * P^T
    bf16x8 vf[2][2];
    #pragma unroll
    for (int dt = 0; dt < 2; ++dt)
      #pragma unroll
      for (int s = 0; s < 2; ++s)
        vf[dt][s] = *(const bf16x8*)(Vp + (size_t)(dt * 32 + lr) * SEQ + kv0 + s * 16 + h * 8);
    // prefetch next K tile
    bf16x8 kn[4];
    if (t + 1 < nt){
      #pragma unroll
      for (int d0 = 0; d0 < 4; ++d0)
        kn[d0] = *(const bf16x8*)(Kp + (size_t)(kv0 + 32 + lr) * HD + d0 * 16 + h * 8);
    }
    // S^T = K * Q^T : lane holds 16 k-values of row q = lane&31
    f32x16 st = {};
    #pragma unroll
    for (int d0 = 0; d0 < 4; ++d0)
      st = __builtin_amdgcn_mfma_f32_32x32x16_bf16(kf[d0], qf[d0], st, 0, 0, 0);
    if (t == nt - 1){
      #pragma unroll
      for (int r = 0; r < 16; ++r){
        int kkl = (r & 3) + 8 * (r >> 2) + 4 * h;
        if (kkl > lr) st[r] = -3.0e38f;
      }
    }
    // row max: in-lane tree + one permlane32_swap
    float mx[8];
    #pragma unroll
    for (int r = 0; r < 8; ++r) mx[r] = fmaxf(st[r], st[r + 8]);
    #pragma unroll
    for (int r = 0; r < 4; ++r) mx[r] = fmaxf(mx[r], mx[r + 4]);
    float m01 = fmaxf(fmaxf(mx[0], mx[1]), fmaxf(mx[2], mx[3]));
    u32x2 mm = plswap(__float_as_uint(m01), __float_as_uint(m01));
    float tm = fmaxf(__uint_as_float(mm.x), __uint_as_float(mm.y));
    // defer-max rescale (THR = 1.0 in pre-scaled units)
    if (__any(tm > mS + 1.0f)){
      float mn = fmaxf(mS, tm);
      float al = __expf(mS - mn);
      mS = mn;
      lS *= al;
      #pragma unroll
      for (int r = 0; r < 16; ++r){ ot0[r] *= al; ot1[r] *= al; }
    }
    // P = exp(S - m), in place
    #pragma unroll
    for (int r = 0; r < 16; ++r)
      st[r] = __expf(st[r] - mS);
    // row sum
    float sm[8];
    #pragma unroll
    for (int r = 0; r < 8; ++r) sm[r] = st[r] + st[r + 8];
    #pragma unroll
    for (int r = 0; r < 4; ++r) sm[r] = sm[r] + sm[r + 4];
    float ps = (sm[0] + sm[1]) + (sm[2] + sm[3]);
    u32x2 ss = plswap(__float_as_uint(ps), __float_as_uint(ps));
    lS += __uint_as_float(ss.x) + __uint_as_float(ss.y);
    // pack P -> bf16 B-frags via cvt_pk + permlane32_swap (T12)
    bf16x8 pf[2];
    #pragma unroll
    for (int s = 0; s < 2; ++s){
      unsigned c0 = cvtpk(st[8 * s + 0], st[8 * s + 1]);
      unsigned c1 = cvtpk(st[8 * s + 2], st[8 * s + 3]);
      unsigned c2 = cvtpk(st[8 * s + 4], st[8 * s + 5]);
      unsigned c3 = cvtpk(st[8 * s + 6], st[8 * s + 7]);
      u32x2 r02 = plswap(c0, c2);
      u32x2 r13 = plswap(c1, c3);
      union { unsigned w[4]; bf16x8 v; } u;
      u.w[0] = r02.x; u.w[1] = r13.x; u.w[2] = r02.y; u.w[3] = r13.y;
      pf[s] = u.v;
    }
    // O^T += V^T * P^T
    #pragma unroll
    for (int s = 0; s < 2; ++s){
      ot0 = __builtin_amdgcn_mfma_f32_32x32x16_bf16(vf[0][s], pf[s], ot0, 0, 0, 0);
      ot1 = __builtin_amdgcn_mfma_f32_32x32x16_bf16(vf[1][s], pf[s], ot1, 0, 0, 0);
    }
    if (t + 1 < nt){
      #pragma unroll
      for (int d0 = 0; d0 < 4; ++d0) kf[d0] = kn[d0];
    }
  }
  // epilogue: lane l holds O^T[d][q=lane&31]; d = dt*32 + 8*rq + 4*h + (0..3)
  int b = bh >> 4, hh = bh & 15;
  float inv = 1.0f / lS;
  unsigned short* outp = AO + ((size_t)(b * SEQ + q0 + lr)) * EMB + hh * HD;
  #pragma unroll
  for (int dt = 0; dt < 2; ++dt){
    #pragma unroll
    for (int rq = 0; rq < 4; ++rq){
      float v0 = (dt ? ot1 : ot0)[rq * 4 + 0] * inv;
      float v1 = (dt ? ot1 : ot0)[rq * 4 + 1] * inv;
      float v2 = (dt ? ot1 : ot0)[rq * 4 + 2] * inv;
      float v3 = (dt ? ot1 : ot0)[rq * 4 + 3] * inv;
      uint2 wv;
      wv.x = cvtpk(v0, v1);
      wv.y = cvtpk(v2, v3);
      int d0 = dt * 32 + 8 * rq + 4 * h;
      *(uint2*)(outp + d0) = wv;
    }
  }
}

extern "C" void kernel_launch(void* const* d_in, const int* in_sizes, int n_in,
                              void* d_out, int out_size, void* d_ws, size_t ws_size,
                              hipStream_t stream){
  const float* x  = (const float*)d_in[0];
  const float* Wq = (const float*)d_in[2];
  const float* Wk = (const float*)d_in[3];
  const float* Wv = (const float*)d_in[4];
  const float* Wo = (const float*)d_in[5];
  float* out = (float*)d_out;

  char* ws = (char*)d_ws;
  size_t off = 0;
  auto alloc = [&](size_t bytes){ void* p = ws + off; off += (bytes + 255) & ~(size_t)255; return p; };
  unsigned short* xb    = (unsigned short*)alloc((size_t)4096 * 1024 * 2);
  unsigned short* wtqkv = (unsigned short*)alloc((size_t)3072 * 1024 * 2);
  unsigned short* wto   = (unsigned short*)alloc((size_t)1024 * 1024 * 2);
  unsigned short* qb    = (unsigned short*)alloc((size_t)4096 * 1024 * 2);
  unsigned short* kb    = (unsigned short*)alloc((size_t)4096 * 1024 * 2);
  unsigned short* vb    = (unsigned short*)alloc((size_t)4096 * 1024 * 2);
  float2*         tb    = (float2*)alloc((size_t)2048 * 32 * 8);
  unsigned short* vt = xb;   // xb dead after QKV GEMM
  unsigned short* ao = vb;   // vb dead after V transpose

  k_convert<<<dim3(2048), dim3(256), 0, stream>>>(x, xb, 524288);
  k_transpose_w<<<dim3(32, 32, 4), dim3(32, 8), 0, stream>>>(Wq, Wk, Wv, Wo, wtqkv, wto);
  k_rope_table<<<dim3(256), dim3(256), 0, stream>>>(tb);
  k_gemm<0><<<dim3(32, 24), dim3(256), 0, stream>>>(xb, wtqkv, qb, kb, vb, nullptr);
  k_rope<<<dim3(16384), dim3(256), 0, stream>>>(qb, kb, tb);
  k_transpose_v<<<dim3(64, 2, 32), dim3(32, 8), 0, stream>>>(vb, vt);
  k_attn<<<dim3(2048), dim3(64), 0, stream>>>(qb, kb, vt, ao);
  k_gemm<1><<<dim3(32, 8), dim3(256), 0, stream>>>(ao, wto, nullptr, nullptr, nullptr, out);
}